// Round 14
// baseline (23.552 us; speedup 1.0000x reference)
//
#include <hip/hip_runtime.h>
#include <hip/hip_bf16.h>
#include <math.h>

// B=4, T=S=512, M=N=512, H=128
#define KDIM 512
#define HDIM 128
#define SDIM 512
#define TOTAL_ROWS 2048
#define INV_SCALE 0.04419417382415922f   // 1/sqrt(512)

// score[b,t,s] = a'[b,t] + c'[b,s]  (both pre-scaled)
//   a'[b,t] = inv_scale * sum_h v[h]   * tanh(q[b,t,:]·W2[h,:])
//   c'[b,s] = inv_scale * sum_h v[H+h] * tanh(k[b,s,:]·W1[h,:])
// ws: [0,2048) a' f32 (query); [2048,4096) c' f32 (keys).
// D1: proj for BOTH sides, full chip, NO LDS staging (direct-global A and B).
// D2: outer broadcast-add.

typedef __attribute__((ext_vector_type(8))) short bf16x8;   // 8 bf16 = 4 VGPRs
typedef __attribute__((ext_vector_type(4))) float f32x4;    // MFMA accumulator

__device__ __forceinline__ float fast_tanh(float x) {
    // tanh(x) = 1 - 2/(e^{2x}+1); ~1e-7 abs error, graceful at +/-inf
    float e = __expf(2.0f * x);
    return 1.0f - 2.0f / (e + 1.0f);
}
__device__ __forceinline__ unsigned short bfbits(float x) {
    return __builtin_bit_cast(unsigned short, __float2bfloat16(x));
}
__device__ __forceinline__ bf16x8 cvt8(const float4 p, const float4 q) {
    bf16x8 r;
    r[0] = (short)bfbits(p.x); r[1] = (short)bfbits(p.y);
    r[2] = (short)bfbits(p.z); r[3] = (short)bfbits(p.w);
    r[4] = (short)bfbits(q.x); r[5] = (short)bfbits(q.y);
    r[6] = (short)bfbits(q.z); r[7] = (short)bfbits(q.w);
    return r;
}

// 256 blocks x 512 thr (8 waves): blk<128 query w/ W2 -> ws[0:2048);
// blk>=128 keys w/ W1 -> ws[2048:4096). 16 rows/block; wave = h-tile h0=16*wave.
// MFMA 16x16x32_bf16, k-bijection (r11/r13-verified): within 32-k step t, lane-group
// g = lane>>4 owns k-slots {t*32+g*4..+3} u {t*32+16+g*4..+3}. Both A (X rows) and
// B (W rows) are loaded DIRECTLY from global f32 with this map: lanes (c16, g) x
// float4 cover 16 rows x full 64B lines -> every line fully used, no LDS, no barrier.
// All 8 waves read the same 32KB X tile (L1-resident); W streams from L2.
// C layout: col = lane&15 (h), row = g*4 + reg (HW-verified r9/m89):
//   acc[r] = dot(X[row0 + g*4 + r], W[h0 + c16]).
__global__ __launch_bounds__(512) void proj_kernel(
    const float* __restrict__ query, const float* __restrict__ keys,
    const float* __restrict__ W1, const float* __restrict__ W2,
    const float* __restrict__ v, float* __restrict__ ws)
{
    const int blk = blockIdx.x;
    const bool is_keys = (blk >= 128);
    const float* __restrict__ X  = is_keys ? keys : query;
    const float* __restrict__ Wf = is_keys ? W1 : W2;
    const float* __restrict__ vv = v + (is_keys ? HDIM : 0);
    float* __restrict__ out = ws + (is_keys ? TOTAL_ROWS : 0);
    const int row0 = (blk & 127) * 16;

    __shared__ float sm_p[8][16];

    const int tid  = threadIdx.x;
    const int wave = tid >> 6;
    const int lane = tid & 63;
    const int c16  = lane & 15;
    const int g    = lane >> 4;
    const int h0   = wave * 16;

    const float* __restrict__ xrow = X  + (size_t)(row0 + c16) * KDIM + g * 4;
    const float* __restrict__ wrow = Wf + (size_t)(h0 + c16) * KDIM + g * 4;

    f32x4 acc = {0.0f, 0.0f, 0.0f, 0.0f};

    // 16 K-steps of 32. Per step: 4 fully-used-line float4 loads + 16 cvt + 1 MFMA.
    #pragma unroll 4
    for (int t = 0; t < 16; ++t) {
        const float4 a0 = *(const float4*)(xrow + t * 32);        // k t*32+g*4..+3
        const float4 a1 = *(const float4*)(xrow + t * 32 + 16);   // k t*32+16+g*4..+3
        const float4 b0 = *(const float4*)(wrow + t * 32);
        const float4 b1 = *(const float4*)(wrow + t * 32 + 16);
        acc = __builtin_amdgcn_mfma_f32_16x16x32_bf16(cvt8(a0, a1), cvt8(b0, b1),
                                                      acc, 0, 0, 0);
    }

    // acc[r] = dot(X[row0+g*4+r], W[h0+c16]); weight by v, tanh, reduce over h.
    const float vh = vv[h0 + c16];
    #pragma unroll
    for (int r = 0; r < 4; ++r) {
        float s = vh * fast_tanh(acc[r]);
        s += __shfl_xor(s, 1, 64);   // reduce over h-columns (lane bits 0-3)
        s += __shfl_xor(s, 2, 64);
        s += __shfl_xor(s, 4, 64);
        s += __shfl_xor(s, 8, 64);
        if (c16 == 0) sm_p[wave][g * 4 + r] = s;
    }
    __syncthreads();

    if (tid < 16) {
        float s = 0.0f;
        #pragma unroll
        for (int w = 0; w < 8; ++w) s += sm_p[w][tid];
        out[row0 + tid] = s * INV_SCALE;
    }
}

// 256 blocks x 256 thr; block = 8 bt-rows (single batch each). c' row stays L1-hot.
__global__ __launch_bounds__(256) void outer_kernel(
    const float* __restrict__ ws, float* __restrict__ out)
{
    const int r0  = blockIdx.x * 8;
    const int b   = r0 >> 9;
    const float4* __restrict__ c4 = (const float4*)(ws + TOTAL_ROWS + (size_t)b * SDIM);
    const int col = threadIdx.x & 127;
    const int rh  = threadIdx.x >> 7;   // 0/1

    #pragma unroll
    for (int rp = 0; rp < 4; ++rp) {
        const int row = r0 + rp * 2 + rh;
        const float a = ws[row];
        const float4 c = c4[col];
        float4 o;
        o.x = a + c.x; o.y = a + c.y; o.z = a + c.z; o.w = a + c.w;
        ((float4*)out)[(size_t)row * (SDIM / 4) + col] = o;
    }
}

extern "C" void kernel_launch(void* const* d_in, const int* in_sizes, int n_in,
                              void* d_out, int out_size, void* d_ws, size_t ws_size,
                              hipStream_t stream) {
    const float* query = (const float*)d_in[0];  // (4,512,512)
    const float* keys  = (const float*)d_in[1];  // (4,512,512)
    const float* W1    = (const float*)d_in[2];  // (128,512)
    const float* W2    = (const float*)d_in[3];  // (128,512)
    const float* v     = (const float*)d_in[4];  // (1,256)
    float* out = (float*)d_out;                  // (4,512,512) f32
    float* ws  = (float*)d_ws;                   // a' + c' (4096 floats)

    proj_kernel<<<256, 512, 0, stream>>>(query, keys, W1, W2, v, ws);
    outer_kernel<<<256, 256, 0, stream>>>(ws, out);
}

// Round 15
// 17.342 us; speedup vs baseline: 1.3581x; 1.3581x over previous
//
#include <hip/hip_runtime.h>
#include <hip/hip_bf16.h>
#include <math.h>

// B=4, T=S=512, M=N=512, H=128
#define KDIM 512
#define HDIM 128
#define SDIM 512
#define TOTAL_ROWS 2048
#define INV_SCALE 0.04419417382415922f   // 1/sqrt(512)

// score[b,t,s] = a'[b,t] + c'[b,s]  (both pre-scaled)
//   a'[b,t] = inv_scale * sum_h v[h]   * tanh(q[b,t,:]·W2[h,:])
//   c'[b,s] = inv_scale * sum_h v[H+h] * tanh(k[b,s,:]·W1[h,:])
// ws: [0,2048) a' f32; [2048,4096) c' f32.
// D1: proj both sides, 256 blocks x 1024 thr (16 waves): wave pair (htile, khalf)
//     K-splits 256/256 -> 4 waves/SIMD with UNCHANGED per-block W traffic.
// D2: outer broadcast-add.

typedef __attribute__((ext_vector_type(8))) short bf16x8;   // 8 bf16 = 4 VGPRs
typedef __attribute__((ext_vector_type(4))) float f32x4;    // MFMA accumulator

__device__ __forceinline__ float fast_tanh(float x) {
    // tanh(x) = 1 - 2/(e^{2x}+1); ~1e-7 abs error, graceful at +/-inf
    float e = __expf(2.0f * x);
    return 1.0f - 2.0f / (e + 1.0f);
}
__device__ __forceinline__ unsigned short bfbits(float x) {
    return __builtin_bit_cast(unsigned short, __float2bfloat16(x));
}
__device__ __forceinline__ bf16x8 cvt8(const float4 p, const float4 q) {
    bf16x8 r;
    r[0] = (short)bfbits(p.x); r[1] = (short)bfbits(p.y);
    r[2] = (short)bfbits(p.z); r[3] = (short)bfbits(p.w);
    r[4] = (short)bfbits(q.x); r[5] = (short)bfbits(q.y);
    r[6] = (short)bfbits(q.z); r[7] = (short)bfbits(q.w);
    return r;
}

// 256 blocks x 1024 thr: blk<128 query w/ W2 -> ws[0:2048); blk>=128 keys w/ W1.
// 16 rows/block. Wave w: htile = w&7 (h0 = 16*htile), khalf = w>>3 (k-offset 256*khalf).
// MFMA 16x16x32_bf16 with the r11/r13-verified k-bijection inside each 32-k step:
// lane-group g owns k-slots {s*32+g*4..+3} u {s*32+16+g*4..+3} (s = global step).
// A staged in LDS bf16 (granule-swizzled by row&7); B = f32 W direct, half-frag
// float4 loads cover FULL 64B lines. K-halves combined pre-tanh via padded LDS.
// C layout: col = lane&15 (h), row = g*4 + reg  ->  acc[r] = X[row0+g*4+r]·W[h0+c16].
__global__ __launch_bounds__(1024) void proj_kernel(
    const float* __restrict__ query, const float* __restrict__ keys,
    const float* __restrict__ W1, const float* __restrict__ W2,
    const float* __restrict__ v, float* __restrict__ ws)
{
    const int blk = blockIdx.x;
    const bool is_keys = (blk >= 128);
    const float* __restrict__ X  = is_keys ? keys : query;
    const float* __restrict__ Wf = is_keys ? W1 : W2;
    const float* __restrict__ vv = v + (is_keys ? HDIM : 0);
    float* __restrict__ out = ws + (is_keys ? TOTAL_ROWS : 0);
    const int row0 = (blk & 127) * 16;

    __shared__ __align__(16) unsigned short sm_x[16 * KDIM];  // 16 KB bf16
    __shared__ float sm_part[8][16][17];                      // padded: conflict-free
    __shared__ float sm_p[8][16];

    const int tid   = threadIdx.x;        // 0..1023
    const int wave  = tid >> 6;           // 0..15
    const int lane  = tid & 63;
    const int c16   = lane & 15;
    const int g     = lane >> 4;
    const int htile = wave & 7;
    const int khalf = wave >> 3;
    const int h0    = htile * 16;

    // ---- Stage X tile: 2048 float4, 2 per thread; granule matches k-bijection. ----
    {
        const float4* __restrict__ src = (const float4*)(X + (size_t)row0 * KDIM);
        #pragma unroll
        for (int i = 0; i < 2; ++i) {
            const int f   = tid + i * 1024;   // row*128 + fr
            const int row = f >> 7;
            const int fr  = f & 127;
            const float4 xv = src[f];
            ushort4 o;
            o.x = bfbits(xv.x); o.y = bfbits(xv.y);
            o.z = bfbits(xv.z); o.w = bfbits(xv.w);
            const int s    = fr >> 3;         // 32-k step 0..15
            const int off4 = fr & 7;
            const int gg   = off4 & 3;        // k-group
            const int half = off4 >> 2;       // 0: k-off 0-15, 1: 16-31
            char* dst = (char*)sm_x + row * 1024
                      + (((s * 4 + gg) ^ (row & 7)) << 4) + half * 8;
            *(ushort4*)dst = o;
        }
    }
    __syncthreads();

    const float* __restrict__ wrow = Wf + (size_t)(h0 + c16) * KDIM + khalf * 256 + g * 4;
    const char* __restrict__ arow = (const char*)sm_x + c16 * 1024;
    const int swz = c16 & 7;

    f32x4 acc = {0.0f, 0.0f, 0.0f, 0.0f};
    // 8 K-steps of 32 (this wave's K-half), fully unrolled: 16 W-loads in flight.
    #pragma unroll
    for (int t = 0; t < 8; ++t) {
        const int s = khalf * 8 + t;                              // global 32-k step
        const float4 b0 = *(const float4*)(wrow + t * 32);        // k s*32+g*4..+3
        const float4 b1 = *(const float4*)(wrow + t * 32 + 16);   // k s*32+16+g*4..+3
        const bf16x8 a = *(const bf16x8*)(arow + (((s * 4 + g) ^ swz) << 4));
        acc = __builtin_amdgcn_mfma_f32_16x16x32_bf16(a, cvt8(b0, b1), acc, 0, 0, 0);
    }

    // ---- Combine K-halves (pre-tanh, linear). ----
    if (khalf == 1) {
        #pragma unroll
        for (int r = 0; r < 4; ++r) sm_part[htile][c16][g * 4 + r] = acc[r];
    }
    __syncthreads();

    if (khalf == 0) {
        const float vh = vv[h0 + c16];
        #pragma unroll
        for (int r = 0; r < 4; ++r) {
            float s = vh * fast_tanh(acc[r] + sm_part[htile][c16][g * 4 + r]);
            s += __shfl_xor(s, 1, 64);   // reduce over h-columns (lane bits 0-3)
            s += __shfl_xor(s, 2, 64);
            s += __shfl_xor(s, 4, 64);
            s += __shfl_xor(s, 8, 64);
            if (c16 == 0) sm_p[htile][g * 4 + r] = s;
        }
    }
    __syncthreads();

    if (tid < 16) {
        float s = 0.0f;
        #pragma unroll
        for (int w = 0; w < 8; ++w) s += sm_p[w][tid];
        out[row0 + tid] = s * INV_SCALE;
    }
}

// 256 blocks x 256 thr; block = 8 bt-rows (single batch each). c' row stays L1-hot.
__global__ __launch_bounds__(256) void outer_kernel(
    const float* __restrict__ ws, float* __restrict__ out)
{
    const int r0  = blockIdx.x * 8;
    const int b   = r0 >> 9;
    const float4* __restrict__ c4 = (const float4*)(ws + TOTAL_ROWS + (size_t)b * SDIM);
    const int col = threadIdx.x & 127;
    const int rh  = threadIdx.x >> 7;   // 0/1

    #pragma unroll
    for (int rp = 0; rp < 4; ++rp) {
        const int row = r0 + rp * 2 + rh;
        const float a = ws[row];
        const float4 c = c4[col];
        float4 o;
        o.x = a + c.x; o.y = a + c.y; o.z = a + c.z; o.w = a + c.w;
        ((float4*)out)[(size_t)row * (SDIM / 4) + col] = o;
    }
}

extern "C" void kernel_launch(void* const* d_in, const int* in_sizes, int n_in,
                              void* d_out, int out_size, void* d_ws, size_t ws_size,
                              hipStream_t stream) {
    const float* query = (const float*)d_in[0];  // (4,512,512)
    const float* keys  = (const float*)d_in[1];  // (4,512,512)
    const float* W1    = (const float*)d_in[2];  // (128,512)
    const float* W2    = (const float*)d_in[3];  // (128,512)
    const float* v     = (const float*)d_in[4];  // (1,256)
    float* out = (float*)d_out;                  // (4,512,512) f32
    float* ws  = (float*)d_ws;                   // a' + c' (4096 floats)

    proj_kernel<<<256, 1024, 0, stream>>>(query, keys, W1, W2, v, ws);
    outer_kernel<<<256, 256, 0, stream>>>(ws, out);
}